// Round 16
// baseline (597.166 us; speedup 1.0000x reference)
//
#include <hip/hip_runtime.h>
#include <hip/hip_fp16.h>
#include <hip/hip_cooperative_groups.h>

namespace cg = cooperative_groups;

constexpr int D = 128;

typedef _Float16 half8 __attribute__((ext_vector_type(8)));
typedef float f32x4 __attribute__((ext_vector_type(4)));

// ---------------- cooperative mega-prologue ----------------
// Phase 1: zero cnt  +  weight fragments (independent work, overlapped)
// Phase 2: degree count (no-return atomics)
// Phase 3: dinv + per-chunk bsum
// Phase 4: bsum scan (redundant per block) + local scan -> rowptr, cursor
// Phase 5: CSR fill + x->fp16 cvt
// Wf[((kk*8 + c)*64 + l)*8 + j] = W[kk*32 + (l>>4)*8 + j][c*16 + (l&15)]
// Wfp = fragment of (W2 @ M1); cp = b2 @ M1 + c1.  Assumes gN <= 256.

template <typename IdxT>
__global__ __launch_bounds__(256) void k_build(
    const int* __restrict__ src, const int* __restrict__ dst, int E, int n, int gN,
    int* __restrict__ cnt, float* __restrict__ dinv, int* __restrict__ bsum,
    int* __restrict__ rowptr, int* __restrict__ cursor, IdxT* __restrict__ csr,
    const float* __restrict__ x, __half* __restrict__ xh, int n4,
    const float* __restrict__ W0, const float* __restrict__ W1,
    const float* __restrict__ W2, const float* __restrict__ M1,
    const float* __restrict__ b2, const float* __restrict__ c1,
    __half* __restrict__ Wf0, __half* __restrict__ Wf1, __half* __restrict__ Wfp,
    float* __restrict__ cp) {
    __shared__ int sb[256];
    __shared__ int sm[256];
    cg::grid_group grid = cg::this_grid();
    int tid = threadIdx.x;
    int bid = blockIdx.x;
    int T = gridDim.x * 256;
    int gid = bid * 256 + tid;

    // ---- phase 1: zero cnt + weight fragments ----
    for (int i = gid; i < n; i += T) cnt[i] = 0;
    for (int q = gid; q < 2 * 16384; q += T) {
        int m = q >> 14;
        int idx = q & 16383;
        int j = idx & 7;
        int l = (idx >> 3) & 63;
        int c = (idx >> 9) & 7;
        int kk = (idx >> 12) & 3;
        int row = kk * 32 + (l >> 4) * 8 + j;
        int col = c * 16 + (l & 15);
        const float* W = (m == 0) ? W0 : W1;
        __half* Wf = (m == 0) ? Wf0 : Wf1;
        Wf[idx] = __float2half(W[row * 128 + col]);
    }
    for (int idx = gid; idx < 16384; idx += T) {
        int j = idx & 7;
        int l = (idx >> 3) & 63;
        int c = (idx >> 9) & 7;
        int kk = (idx >> 12) & 3;
        int row = kk * 32 + (l >> 4) * 8 + j;
        int col = c * 16 + (l & 15);
        float acc = 0.f;
        for (int k = 0; k < 128; ++k)
            acc = fmaf(W2[row * 128 + k], M1[k * 128 + col], acc);
        Wfp[idx] = __float2half(acc);
    }
    if (gid < 128) {
        float acc = c1[gid];
        for (int k = 0; k < 128; ++k) acc = fmaf(b2[k], M1[k * 128 + gid], acc);
        cp[gid] = acc;
    }
    grid.sync();

    // ---- phase 2: count ----
    for (int e = gid; e < E; e += T) atomicAdd(&cnt[dst[e]], 1);
    grid.sync();

    // ---- phase 3: dinv + per-chunk bsum ----
    for (int i = gid; i < n; i += T) dinv[i] = rsqrtf((float)(cnt[i] + 1));
    if (bid < gN) {
        int i = bid * 256 + tid;
        sm[tid] = (i < n) ? cnt[i] : 0;
        __syncthreads();
        for (int off = 128; off > 0; off >>= 1) {
            if (tid < off) sm[tid] += sm[tid + off];
            __syncthreads();
        }
        if (tid == 0) bsum[bid] = sm[0];
    }
    grid.sync();

    // ---- phase 4: rowptr/cursor ----
    if (bid < gN) {
        int bv = (tid < gN) ? bsum[tid] : 0;
        sb[tid] = bv;
        __syncthreads();
        for (int off = 1; off < 256; off <<= 1) {
            int t = (tid >= off) ? sb[tid - off] : 0;
            __syncthreads();
            sb[tid] += t;
            __syncthreads();
        }
        int blockoff = (bid > 0) ? sb[bid - 1] : 0;
        int i = bid * 256 + tid;
        int v = (i < n) ? cnt[i] : 0;
        sm[tid] = v;
        __syncthreads();
        for (int off = 1; off < 256; off <<= 1) {
            int t = (tid >= off) ? sm[tid - off] : 0;
            __syncthreads();
            sm[tid] += t;
            __syncthreads();
        }
        if (i < n) {
            int rp = blockoff + sm[tid] - v;
            rowptr[i] = rp;
            cursor[i] = rp;
        }
        if (bid == 0 && tid == 0) rowptr[n] = sb[gN - 1];
    }
    grid.sync();

    // ---- phase 5: CSR fill + x->fp16 cvt ----
    for (int e = gid; e < E; e += T) {
        int s = src[e], d = dst[e];
        int p = atomicAdd(&cursor[d], 1);
        csr[p] = (IdxT)s;
    }
    for (int i = gid; i < n4; i += T) {
        float4 v = reinterpret_cast<const float4*>(x)[i];
        float dd = dinv[i >> 5];
        __half ho[4] = {__float2half(v.x * dd), __float2half(v.y * dd),
                        __float2half(v.z * dd), __float2half(v.w * dd)};
        reinterpret_cast<uint2*>(xh)[i] = *reinterpret_cast<uint2*>(ho);
    }
}

// ---------------- fused agg + MFMA GEMM (unchanged from R14) ----------------

__device__ inline void accm(float* a, uint4 g, float m) {
    float2 p0 = __half22float2(*reinterpret_cast<const __half2*>(&g.x));
    float2 p1 = __half22float2(*reinterpret_cast<const __half2*>(&g.y));
    float2 p2 = __half22float2(*reinterpret_cast<const __half2*>(&g.z));
    float2 p3 = __half22float2(*reinterpret_cast<const __half2*>(&g.w));
    a[0] = fmaf(m, p0.x, a[0]);
    a[1] = fmaf(m, p0.y, a[1]);
    a[2] = fmaf(m, p1.x, a[2]);
    a[3] = fmaf(m, p1.y, a[3]);
    a[4] = fmaf(m, p2.x, a[4]);
    a[5] = fmaf(m, p2.y, a[5]);
    a[6] = fmaf(m, p3.x, a[6]);
    a[7] = fmaf(m, p3.y, a[7]);
}

template <int MODE, typename IdxT>
__global__ __launch_bounds__(256) void k_fused(const uint4* __restrict__ Ah4,  // [n*16]
                                               const int* __restrict__ rowptr,
                                               const IdxT* __restrict__ csr,
                                               const float* __restrict__ dinv,
                                               const __half* __restrict__ Wf,
                                               const float* __restrict__ bias,
                                               const float* __restrict__ m2,
                                               const float* __restrict__ m2b,
                                               void* __restrict__ outv, int n) {
    __shared__ uint4 Ht[32 * 16];  // [row][block], block XOR-swizzled by row&7
    __shared__ float ph[2][32];    // MODE 1 partial dots per col-half
    int tid = threadIdx.x;
    int wv = tid >> 6;
    int lane = tid & 63;
    int r0 = blockIdx.x * 32;

    // ---- phase 1: aggregate 32 rows ----
    int half = lane >> 5;
    int l31 = lane & 31;
    int qg2 = (lane >> 4) & 1;
    int fl = lane & 15;
    for (int it = 0; it < 4; ++it) {
        int lr = wv * 8 + it * 2 + half;  // local row 0..31
        int i = r0 + lr;
        if (i >= n) i = n - 1;  // clamp: LDS row still unique (lr)
        float a[8];
#pragma unroll
        for (int j = 0; j < 8; ++j) a[j] = 0.f;
        int beg = rowptr[i], end = rowptr[i + 1];
        for (int base = beg; base < end; base += 32) {
            int c2 = end - base;
            if (c2 > 32) c2 = 32;
            int idxv = (base + l31 < end) ? (int)csr[base + l31] : 0;
            for (int e = 0; e < c2; e += 8) {
                int k0 = e + qg2;
                int k1 = e + qg2 + 2;
                int k2 = e + qg2 + 4;
                int k3 = e + qg2 + 6;
                int s0 = __shfl(idxv, half * 32 + k0);
                int s1 = __shfl(idxv, half * 32 + k1);
                int s2 = __shfl(idxv, half * 32 + k2);
                int s3 = __shfl(idxv, half * 32 + k3);
                uint4 g0 = Ah4[s0 * 16 + fl];
                uint4 g1 = Ah4[s1 * 16 + fl];
                uint4 g2 = Ah4[s2 * 16 + fl];
                uint4 g3 = Ah4[s3 * 16 + fl];
                float m0 = (k0 < c2) ? 1.f : 0.f;
                float m1 = (k1 < c2) ? 1.f : 0.f;
                float m2_ = (k2 < c2) ? 1.f : 0.f;
                float m3 = (k3 < c2) ? 1.f : 0.f;
                accm(a, g0, m0);
                accm(a, g1, m1);
                accm(a, g2, m2_);
                accm(a, g3, m3);
            }
        }
#pragma unroll
        for (int j = 0; j < 8; ++j) a[j] += __shfl_xor(a[j], 16);
        if (qg2 == 0) {
            uint4 gs = Ah4[i * 16 + fl];
            accm(a, gs, 1.f);  // self term
            float di = dinv[i];
            __half ho[8];
#pragma unroll
            for (int j = 0; j < 8; ++j) ho[j] = __float2half(di * a[j]);
            Ht[lr * 16 + (fl ^ (lr & 7))] = *reinterpret_cast<const uint4*>(ho);
        }
    }
    __syncthreads();

    // ---- phase 2: MFMA GEMM from LDS ----
    int w4 = wv & 1;   // row tile (16 rows)
    int ch = wv >> 1;  // col half (64 cols)
    int rr = w4 * 16 + (lane & 15);

    f32x4 acc[4];
#pragma unroll
    for (int c = 0; c < 4; ++c) acc[c] = (f32x4){0.f, 0.f, 0.f, 0.f};

#pragma unroll
    for (int kk = 0; kk < 4; ++kk) {
        int bk = kk * 4 + (lane >> 4);
        half8 a = *reinterpret_cast<const half8*>(&Ht[rr * 16 + (bk ^ (rr & 7))]);
#pragma unroll
        for (int c = 0; c < 4; ++c) {
            int gc = ch * 4 + c;
            half8 b = *reinterpret_cast<const half8*>(&Wf[((kk * 8 + gc) * 64 + lane) * 8]);
            acc[c] = __builtin_amdgcn_mfma_f32_16x16x32_f16(a, b, acc[c], 0, 0, 0);
        }
    }

    float bv[4];
#pragma unroll
    for (int c = 0; c < 4; ++c) bv[c] = bias[ch * 64 + c * 16 + (lane & 15)];

    if (MODE == 0) {
        __half* outh = (__half*)outv;
#pragma unroll
        for (int reg = 0; reg < 4; ++reg) {
            int r = r0 + w4 * 16 + (lane >> 4) * 4 + reg;
            if (r < n) {
                float dr = dinv[r];
#pragma unroll
                for (int c = 0; c < 4; ++c) {
                    float v = dr * fmaxf(acc[c][reg] + bv[c], 0.f);
                    outh[r * 128 + ch * 64 + c * 16 + (lane & 15)] = __float2half(v);
                }
            }
        }
    } else {
        float* out = (float*)outv;
        float mv[4];
#pragma unroll
        for (int c = 0; c < 4; ++c) mv[c] = m2[ch * 64 + c * 16 + (lane & 15)];
#pragma unroll
        for (int reg = 0; reg < 4; ++reg) {
            float p = 0.f;
#pragma unroll
            for (int c = 0; c < 4; ++c)
                p = fmaf(fmaxf(acc[c][reg] + bv[c], 0.f), mv[c], p);
            p += __shfl_xor(p, 1);
            p += __shfl_xor(p, 2);
            p += __shfl_xor(p, 4);
            p += __shfl_xor(p, 8);
            if ((lane & 15) == 0) ph[ch][w4 * 16 + (lane >> 4) * 4 + reg] = p;
        }
        __syncthreads();
        if (tid < 32) {
            int r = r0 + tid;
            if (r < n) out[r] = ph[0][tid] + ph[1][tid] + m2b[0];
        }
    }
}

// ---------------- launch ----------------

extern "C" void kernel_launch(void* const* d_in, const int* in_sizes, int n_in,
                              void* d_out, int out_size, void* d_ws, size_t ws_size,
                              hipStream_t stream) {
    const float* x = (const float*)d_in[0];
    const int* ei = (const int*)d_in[1];
    const float* W0 = (const float*)d_in[2];
    const float* b0 = (const float*)d_in[3];
    const float* W1 = (const float*)d_in[4];
    const float* b1 = (const float*)d_in[5];
    const float* W2 = (const float*)d_in[6];
    const float* b2 = (const float*)d_in[7];
    const float* M1 = (const float*)d_in[8];
    const float* c1 = (const float*)d_in[9];
    const float* m2 = (const float*)d_in[10];
    const float* m2b = (const float*)d_in[11];
    float* out = (float*)d_out;

    int N = in_sizes[0] / D;
    int E = in_sizes[1] / 2;
    const int* src = ei;
    const int* dst = ei + E;

    char* ws = (char*)d_ws;
    size_t off = 0;
    auto alloc = [&](size_t bytes) -> void* {
        void* p = ws + off;
        off += (bytes + 255) & ~(size_t)255;
        return p;
    };

    int gN = (N + 255) / 256;
    int gFused = (N + 31) / 32;
    int nElem4 = N * D / 4;

    __half* xh = (__half*)alloc((size_t)N * D * 2);     // fp16 dinv-scaled x
    __half* bufA = (__half*)alloc((size_t)N * D * 2);   // layer outputs (ping)
    __half* bufB = (__half*)alloc((size_t)N * D * 2);   // layer outputs (pong)
    int* cnt = (int*)alloc((size_t)N * 4);
    float* dinv = (float*)alloc((size_t)N * 4);
    int* rowptr = (int*)alloc((size_t)(N + 1) * 4);
    int* cursor = (int*)alloc((size_t)N * 4);
    void* csr = alloc((size_t)E * 4);  // ushort (E*2) or uint (E*4)
    float* cp = (float*)alloc((size_t)D * 4);
    __half* Wf0 = (__half*)alloc((size_t)D * D * 2);
    __half* Wf1 = (__half*)alloc((size_t)D * D * 2);
    __half* Wfp = (__half*)alloc((size_t)D * D * 2);
    int* bsum = (int*)alloc((size_t)gN * 4);

    bool small_idx = (N <= 65535);

    // cooperative mega-prologue (1024 blocks: all resident, 4/CU)
    {
        ushort* csr_s = (ushort*)csr;
        uint* csr_u = (uint*)csr;
        void* args_s[] = {(void*)&src,  (void*)&dst,  (void*)&E,     (void*)&N,
                          (void*)&gN,   (void*)&cnt,  (void*)&dinv,  (void*)&bsum,
                          (void*)&rowptr, (void*)&cursor, (void*)&csr_s, (void*)&x,
                          (void*)&xh,   (void*)&nElem4, (void*)&W0,  (void*)&W1,
                          (void*)&W2,   (void*)&M1,   (void*)&b2,    (void*)&c1,
                          (void*)&Wf0,  (void*)&Wf1,  (void*)&Wfp,   (void*)&cp};
        void* args_u[] = {(void*)&src,  (void*)&dst,  (void*)&E,     (void*)&N,
                          (void*)&gN,   (void*)&cnt,  (void*)&dinv,  (void*)&bsum,
                          (void*)&rowptr, (void*)&cursor, (void*)&csr_u, (void*)&x,
                          (void*)&xh,   (void*)&nElem4, (void*)&W0,  (void*)&W1,
                          (void*)&W2,   (void*)&M1,   (void*)&b2,    (void*)&c1,
                          (void*)&Wf0,  (void*)&Wf1,  (void*)&Wfp,   (void*)&cp};
        if (small_idx)
            hipLaunchCooperativeKernel((const void*)k_build<ushort>, dim3(1024),
                                       dim3(256), args_s, 0, stream);
        else
            hipLaunchCooperativeKernel((const void*)k_build<uint>, dim3(1024),
                                       dim3(256), args_u, 0, stream);
    }

    auto fused0 = [&](const __half* in_h, const __half* Wf, const float* b,
                      __half* out_h) {
        if (small_idx)
            k_fused<0, ushort><<<gFused, 256, 0, stream>>>(
                (const uint4*)in_h, rowptr, (const ushort*)csr, dinv, Wf, b, nullptr,
                nullptr, out_h, N);
        else
            k_fused<0, uint><<<gFused, 256, 0, stream>>>(
                (const uint4*)in_h, rowptr, (const uint*)csr, dinv, Wf, b, nullptr,
                nullptr, out_h, N);
    };

    // layer 0
    fused0(xh, Wf0, b0, bufA);
    // layer 1
    fused0(bufA, Wf1, b1, bufB);
    // layer 2 + fused MLP head
    if (small_idx)
        k_fused<1, ushort><<<gFused, 256, 0, stream>>>(
            (const uint4*)bufB, rowptr, (const ushort*)csr, dinv, Wfp, cp, m2, m2b, out,
            N);
    else
        k_fused<1, uint><<<gFused, 256, 0, stream>>>(
            (const uint4*)bufB, rowptr, (const uint*)csr, dinv, Wfp, cp, m2, m2b, out,
            N);
}

// Round 17
// 171.697 us; speedup vs baseline: 3.4780x; 3.4780x over previous
//
#include <hip/hip_runtime.h>
#include <hip/hip_fp16.h>

constexpr int D = 128;

typedef _Float16 half8 __attribute__((ext_vector_type(8)));
typedef float f32x4 __attribute__((ext_vector_type(4)));

// ---------------- small utility ----------------

__global__ void k_zero(int4* __restrict__ p, int n4) {
    int i = blockIdx.x * 256 + threadIdx.x;
    if (i < n4) p[i] = make_int4(0, 0, 0, 0);
}

// ---------------- CSR build ----------------

__global__ void k_count(const int* __restrict__ dst, int* __restrict__ cnt, int E) {
    int e = blockIdx.x * 256 + threadIdx.x;
    if (e < E) atomicAdd(&cnt[dst[e]], 1);
}

// dinv + per-block sum in one pass over cnt
__global__ __launch_bounds__(256) void k_deg_stats(const int* __restrict__ cnt,
                                                   float* __restrict__ dinv,
                                                   int* __restrict__ bsum, int n) {
    __shared__ int sm[256];
    int tid = threadIdx.x;
    int i = blockIdx.x * 256 + tid;
    int c = (i < n) ? cnt[i] : 0;
    if (i < n) dinv[i] = rsqrtf((float)(c + 1));  // +1 self-loop
    sm[tid] = c;
    __syncthreads();
    for (int off = 128; off > 0; off >>= 1) {
        if (tid < off) sm[tid] += sm[tid + off];
        __syncthreads();
    }
    if (tid == 0) bsum[blockIdx.x] = sm[0];
}

// local scan + redundant per-block scan of bsum (nb <= 256) -> rowptr, cursor
__global__ __launch_bounds__(256) void k_local_scan2(const int* __restrict__ cnt,
                                                     const int* __restrict__ bsum, int nb,
                                                     int* __restrict__ rowptr,
                                                     int* __restrict__ cursor, int n) {
    __shared__ int sb[256];
    __shared__ int sm[256];
    int tid = threadIdx.x;
    int bid = blockIdx.x;
    int bv = (tid < nb) ? bsum[tid] : 0;
    sb[tid] = bv;
    __syncthreads();
    for (int off = 1; off < 256; off <<= 1) {
        int t = (tid >= off) ? sb[tid - off] : 0;
        __syncthreads();
        sb[tid] += t;
        __syncthreads();
    }
    int blockoff = (bid > 0) ? sb[bid - 1] : 0;
    int i = bid * 256 + tid;
    int v = (i < n) ? cnt[i] : 0;
    sm[tid] = v;
    __syncthreads();
    for (int off = 1; off < 256; off <<= 1) {
        int t = (tid >= off) ? sm[tid - off] : 0;
        __syncthreads();
        sm[tid] += t;
        __syncthreads();
    }
    if (i < n) {
        int rp = blockoff + sm[tid] - v;
        rowptr[i] = rp;
        cursor[i] = rp;
    }
    if (bid == 0 && tid == 0) rowptr[n] = sb[nb - 1];
}

// ---------------- mega-prep: csr fill + x->fp16 cvt + weight fragments ----------------
// Wf[((kk*8 + c)*64 + l)*8 + j] = W[kk*32 + (l>>4)*8 + j][c*16 + (l&15)]
// Wfp computed directly as fragment of (W2 @ M1); cp = b2 @ M1 + c1.

template <typename IdxT>
__global__ __launch_bounds__(256) void k_prep(
    const int* __restrict__ src, const int* __restrict__ dst, int* __restrict__ cursor,
    IdxT* __restrict__ csr, int E, const float* __restrict__ x,
    const float* __restrict__ dinv, __half* __restrict__ xh, int n4,
    const float* __restrict__ W0, const float* __restrict__ W1,
    const float* __restrict__ W2, const float* __restrict__ M1,
    const float* __restrict__ b2, const float* __restrict__ c1,
    __half* __restrict__ Wf0, __half* __restrict__ Wf1, __half* __restrict__ Wfp,
    float* __restrict__ cp) {
    int T = gridDim.x * 256;
    int gid = blockIdx.x * 256 + threadIdx.x;

    // --- section 1: CSR fill ---
    for (int e = gid; e < E; e += T) {
        int s = src[e], d = dst[e];
        int p = atomicAdd(&cursor[d], 1);
        csr[p] = (IdxT)s;
    }

    // --- section 2: x -> fp16 with dinv pre-scale (4 elems/thread) ---
    for (int i = gid; i < n4; i += T) {
        float4 v = reinterpret_cast<const float4*>(x)[i];
        float dd = dinv[i >> 5];
        __half ho[4] = {__float2half(v.x * dd), __float2half(v.y * dd),
                        __float2half(v.z * dd), __float2half(v.w * dd)};
        reinterpret_cast<uint2*>(xh)[i] = *reinterpret_cast<uint2*>(ho);
    }

    // --- section 3: W0/W1 fragment relayout (2*16384 elems) ---
    for (int q = gid; q < 2 * 16384; q += T) {
        int m = q >> 14;
        int idx = q & 16383;
        int j = idx & 7;
        int l = (idx >> 3) & 63;
        int c = (idx >> 9) & 7;
        int kk = (idx >> 12) & 3;
        int row = kk * 32 + (l >> 4) * 8 + j;
        int col = c * 16 + (l & 15);
        const float* W = (m == 0) ? W0 : W1;
        __half* Wf = (m == 0) ? Wf0 : Wf1;
        Wf[idx] = __float2half(W[row * 128 + col]);
    }

    // --- section 4: Wfp fragment = fragment of (W2 @ M1) ---
    for (int idx = gid; idx < 16384; idx += T) {
        int j = idx & 7;
        int l = (idx >> 3) & 63;
        int c = (idx >> 9) & 7;
        int kk = (idx >> 12) & 3;
        int row = kk * 32 + (l >> 4) * 8 + j;
        int col = c * 16 + (l & 15);
        float acc = 0.f;
        for (int k = 0; k < 128; ++k)
            acc = fmaf(W2[row * 128 + k], M1[k * 128 + col], acc);
        Wfp[idx] = __float2half(acc);
    }

    // --- section 5: cp = b2 @ M1 + c1 ---
    if (gid < 128) {
        float acc = c1[gid];
        for (int k = 0; k < 128; ++k) acc = fmaf(b2[k], M1[k * 128 + gid], acc);
        cp[gid] = acc;
    }
}

// ---------------- fused agg + MFMA GEMM ----------------
// Block: 256 thr (4 waves), 32 rows. LDS: Ht 32x16 uint4 (8 KB, XOR-swizzled).
// Phase 1 (R13 gather): wave wv handles local rows wv*8..wv*8+7 (4 iters x 2 rows,
//   half-wave per row, 2 edge subgroups x 16 feature lanes, 4 gathers in flight).
//   t_i = fp16(dinv_i * (sum g_j + g_i)) written to LDS block (fl ^ (row&7)).
// Phase 2: wave wv: row tile (wv&1)*16, col half (wv>>1)*64. A-frags from LDS,
//   B-frags from global Wf. 16 x mfma_f32_16x16x32_f16 per wave.
// MODE 0: out[N,128] = fp16( dinv[r] * relu(h) )   (pre-scaled for next agg)
// MODE 1: out[N,1]   = relu(h) . m2 + m2b[0]       (fp32, cross-half via LDS)

__device__ inline void accm(float* a, uint4 g, float m) {
    float2 p0 = __half22float2(*reinterpret_cast<const __half2*>(&g.x));
    float2 p1 = __half22float2(*reinterpret_cast<const __half2*>(&g.y));
    float2 p2 = __half22float2(*reinterpret_cast<const __half2*>(&g.z));
    float2 p3 = __half22float2(*reinterpret_cast<const __half2*>(&g.w));
    a[0] = fmaf(m, p0.x, a[0]);
    a[1] = fmaf(m, p0.y, a[1]);
    a[2] = fmaf(m, p1.x, a[2]);
    a[3] = fmaf(m, p1.y, a[3]);
    a[4] = fmaf(m, p2.x, a[4]);
    a[5] = fmaf(m, p2.y, a[5]);
    a[6] = fmaf(m, p3.x, a[6]);
    a[7] = fmaf(m, p3.y, a[7]);
}

template <int MODE, typename IdxT>
__global__ __launch_bounds__(256) void k_fused(const uint4* __restrict__ Ah4,  // [n*16]
                                               const int* __restrict__ rowptr,
                                               const IdxT* __restrict__ csr,
                                               const float* __restrict__ dinv,
                                               const __half* __restrict__ Wf,
                                               const float* __restrict__ bias,
                                               const float* __restrict__ m2,
                                               const float* __restrict__ m2b,
                                               void* __restrict__ outv, int n) {
    __shared__ uint4 Ht[32 * 16];  // [row][block], block XOR-swizzled by row&7
    __shared__ float ph[2][32];    // MODE 1 partial dots per col-half
    int tid = threadIdx.x;
    int wv = tid >> 6;
    int lane = tid & 63;
    int r0 = blockIdx.x * 32;

    // ---- phase 1: aggregate 32 rows ----
    int half = lane >> 5;
    int l31 = lane & 31;
    int qg2 = (lane >> 4) & 1;
    int fl = lane & 15;
    for (int it = 0; it < 4; ++it) {
        int lr = wv * 8 + it * 2 + half;  // local row 0..31
        int i = r0 + lr;
        if (i >= n) i = n - 1;  // clamp: LDS row still unique (lr)
        float a[8];
#pragma unroll
        for (int j = 0; j < 8; ++j) a[j] = 0.f;
        int beg = rowptr[i], end = rowptr[i + 1];
        for (int base = beg; base < end; base += 32) {
            int c2 = end - base;
            if (c2 > 32) c2 = 32;
            int idxv = (base + l31 < end) ? (int)csr[base + l31] : 0;
            for (int e = 0; e < c2; e += 8) {
                int k0 = e + qg2;
                int k1 = e + qg2 + 2;
                int k2 = e + qg2 + 4;
                int k3 = e + qg2 + 6;
                int s0 = __shfl(idxv, half * 32 + k0);
                int s1 = __shfl(idxv, half * 32 + k1);
                int s2 = __shfl(idxv, half * 32 + k2);
                int s3 = __shfl(idxv, half * 32 + k3);
                uint4 g0 = Ah4[s0 * 16 + fl];
                uint4 g1 = Ah4[s1 * 16 + fl];
                uint4 g2 = Ah4[s2 * 16 + fl];
                uint4 g3 = Ah4[s3 * 16 + fl];
                float m0 = (k0 < c2) ? 1.f : 0.f;
                float m1 = (k1 < c2) ? 1.f : 0.f;
                float m2_ = (k2 < c2) ? 1.f : 0.f;
                float m3 = (k3 < c2) ? 1.f : 0.f;
                accm(a, g0, m0);
                accm(a, g1, m1);
                accm(a, g2, m2_);
                accm(a, g3, m3);
            }
        }
#pragma unroll
        for (int j = 0; j < 8; ++j) a[j] += __shfl_xor(a[j], 16);
        if (qg2 == 0) {
            uint4 gs = Ah4[i * 16 + fl];
            accm(a, gs, 1.f);  // self term
            float di = dinv[i];
            __half ho[8];
#pragma unroll
            for (int j = 0; j < 8; ++j) ho[j] = __float2half(di * a[j]);
            Ht[lr * 16 + (fl ^ (lr & 7))] = *reinterpret_cast<const uint4*>(ho);
        }
    }
    __syncthreads();

    // ---- phase 2: MFMA GEMM from LDS ----
    int w4 = wv & 1;   // row tile (16 rows)
    int ch = wv >> 1;  // col half (64 cols)
    int rr = w4 * 16 + (lane & 15);

    f32x4 acc[4];
#pragma unroll
    for (int c = 0; c < 4; ++c) acc[c] = (f32x4){0.f, 0.f, 0.f, 0.f};

#pragma unroll
    for (int kk = 0; kk < 4; ++kk) {
        int bk = kk * 4 + (lane >> 4);
        half8 a = *reinterpret_cast<const half8*>(&Ht[rr * 16 + (bk ^ (rr & 7))]);
#pragma unroll
        for (int c = 0; c < 4; ++c) {
            int gc = ch * 4 + c;
            half8 b = *reinterpret_cast<const half8*>(&Wf[((kk * 8 + gc) * 64 + lane) * 8]);
            acc[c] = __builtin_amdgcn_mfma_f32_16x16x32_f16(a, b, acc[c], 0, 0, 0);
        }
    }

    float bv[4];
#pragma unroll
    for (int c = 0; c < 4; ++c) bv[c] = bias[ch * 64 + c * 16 + (lane & 15)];

    if (MODE == 0) {
        __half* outh = (__half*)outv;
#pragma unroll
        for (int reg = 0; reg < 4; ++reg) {
            int r = r0 + w4 * 16 + (lane >> 4) * 4 + reg;
            if (r < n) {
                float dr = dinv[r];
#pragma unroll
                for (int c = 0; c < 4; ++c) {
                    float v = dr * fmaxf(acc[c][reg] + bv[c], 0.f);
                    outh[r * 128 + ch * 64 + c * 16 + (lane & 15)] = __float2half(v);
                }
            }
        }
    } else {
        float* out = (float*)outv;
        float mv[4];
#pragma unroll
        for (int c = 0; c < 4; ++c) mv[c] = m2[ch * 64 + c * 16 + (lane & 15)];
#pragma unroll
        for (int reg = 0; reg < 4; ++reg) {
            float p = 0.f;
#pragma unroll
            for (int c = 0; c < 4; ++c)
                p = fmaf(fmaxf(acc[c][reg] + bv[c], 0.f), mv[c], p);
            p += __shfl_xor(p, 1);
            p += __shfl_xor(p, 2);
            p += __shfl_xor(p, 4);
            p += __shfl_xor(p, 8);
            if ((lane & 15) == 0) ph[ch][w4 * 16 + (lane >> 4) * 4 + reg] = p;
        }
        __syncthreads();
        if (tid < 32) {
            int r = r0 + tid;
            if (r < n) out[r] = ph[0][tid] + ph[1][tid] + m2b[0];
        }
    }
}

// ---------------- launch ----------------

extern "C" void kernel_launch(void* const* d_in, const int* in_sizes, int n_in,
                              void* d_out, int out_size, void* d_ws, size_t ws_size,
                              hipStream_t stream) {
    const float* x = (const float*)d_in[0];
    const int* ei = (const int*)d_in[1];
    const float* W0 = (const float*)d_in[2];
    const float* b0 = (const float*)d_in[3];
    const float* W1 = (const float*)d_in[4];
    const float* b1 = (const float*)d_in[5];
    const float* W2 = (const float*)d_in[6];
    const float* b2 = (const float*)d_in[7];
    const float* M1 = (const float*)d_in[8];
    const float* c1 = (const float*)d_in[9];
    const float* m2 = (const float*)d_in[10];
    const float* m2b = (const float*)d_in[11];
    float* out = (float*)d_out;

    int N = in_sizes[0] / D;
    int E = in_sizes[1] / 2;
    const int* src = ei;
    const int* dst = ei + E;

    char* ws = (char*)d_ws;
    size_t off = 0;
    auto alloc = [&](size_t bytes) -> void* {
        void* p = ws + off;
        off += (bytes + 255) & ~(size_t)255;
        return p;
    };

    int gN = (N + 255) / 256;
    int gFused = (N + 31) / 32;
    int nElem4 = N * D / 4;

    __half* xh = (__half*)alloc((size_t)N * D * 2);     // fp16 dinv-scaled x
    __half* bufA = (__half*)alloc((size_t)N * D * 2);   // layer outputs (ping)
    __half* bufB = (__half*)alloc((size_t)N * D * 2);   // layer outputs (pong)
    int* cnt = (int*)alloc((size_t)N * 4);
    float* dinv = (float*)alloc((size_t)N * 4);
    int* rowptr = (int*)alloc((size_t)(N + 1) * 4);
    int* cursor = (int*)alloc((size_t)N * 4);
    void* csr = alloc((size_t)E * 4);  // ushort (E*2) or uint (E*4)
    float* cp = (float*)alloc((size_t)D * 4);
    __half* Wf0 = (__half*)alloc((size_t)D * D * 2);
    __half* Wf1 = (__half*)alloc((size_t)D * D * 2);
    __half* Wfp = (__half*)alloc((size_t)D * D * 2);
    int* bsum = (int*)alloc((size_t)gN * 4);

    bool small_idx = (N <= 65535);

    int zc = (N + 3) / 4;
    k_zero<<<(zc + 255) / 256, 256, 0, stream>>>((int4*)cnt, zc);
    k_count<<<(E + 255) / 256, 256, 0, stream>>>(dst, cnt, E);
    k_deg_stats<<<gN, 256, 0, stream>>>(cnt, dinv, bsum, N);
    k_local_scan2<<<gN, 256, 0, stream>>>(cnt, bsum, gN, rowptr, cursor, N);
    if (small_idx)
        k_prep<ushort><<<2048, 256, 0, stream>>>(src, dst, cursor, (ushort*)csr, E, x,
                                                 dinv, xh, nElem4, W0, W1, W2, M1, b2,
                                                 c1, Wf0, Wf1, Wfp, cp);
    else
        k_prep<uint><<<2048, 256, 0, stream>>>(src, dst, cursor, (uint*)csr, E, x, dinv,
                                               xh, nElem4, W0, W1, W2, M1, b2, c1, Wf0,
                                               Wf1, Wfp, cp);

    auto fused0 = [&](const __half* in_h, const __half* Wf, const float* b,
                      __half* out_h) {
        if (small_idx)
            k_fused<0, ushort><<<gFused, 256, 0, stream>>>(
                (const uint4*)in_h, rowptr, (const ushort*)csr, dinv, Wf, b, nullptr,
                nullptr, out_h, N);
        else
            k_fused<0, uint><<<gFused, 256, 0, stream>>>(
                (const uint4*)in_h, rowptr, (const uint*)csr, dinv, Wf, b, nullptr,
                nullptr, out_h, N);
    };

    // layer 0
    fused0(xh, Wf0, b0, bufA);
    // layer 1
    fused0(bufA, Wf1, b1, bufB);
    // layer 2 + fused MLP head
    if (small_idx)
        k_fused<1, ushort><<<gFused, 256, 0, stream>>>(
            (const uint4*)bufB, rowptr, (const ushort*)csr, dinv, Wfp, cp, m2, m2b, out,
            N);
    else
        k_fused<1, uint><<<gFused, 256, 0, stream>>>(
            (const uint4*)bufB, rowptr, (const uint*)csr, dinv, Wfp, cp, m2, m2b, out,
            N);
}